// Round 25
// baseline (125.919 us; speedup 1.0000x reference)
//
#include <hip/hip_runtime.h>

typedef unsigned short u16;
typedef unsigned int u32;
typedef __bf16 bf16x8 __attribute__((ext_vector_type(8)));
typedef unsigned short u16x8v __attribute__((ext_vector_type(8)));
typedef unsigned short u16x4v __attribute__((ext_vector_type(4)));
typedef unsigned int u32x4 __attribute__((ext_vector_type(4)));
typedef float f32x4 __attribute__((ext_vector_type(4)));
typedef float f32x16 __attribute__((ext_vector_type(16)));

#define SEQ 2048
#define NH 16
#define HD 64
#define DIMM 1024
// softmax scale folded into Q: 1/sqrt(64) * log2(e)
#define QSCALE 0.18033688f
// defer-max threshold in log2 units (= 8 nats)
#define DEFER_THR 11.5417f

__device__ __forceinline__ u16 f2bf(float f) {
  unsigned u = __builtin_bit_cast(unsigned, f);
  u += 0x7fffu + ((u >> 16) & 1u);
  return (u16)(u >> 16);
}
__device__ __forceinline__ float bf2f(u16 b) {
  return __builtin_bit_cast(float, ((unsigned)b) << 16);
}
// RTNE pack of two f32 -> packed bf16 pair, single HW instruction
__device__ __forceinline__ u32 cvtpk(float a, float b) {
  u32 r;
  asm("v_cvt_pk_bf16_f32 %0, %1, %2" : "=v"(r) : "v"(a), "v"(b));
  return r;
}

// async global->LDS, 16B per lane; LDS dest = wave-uniform base + lane*16
__device__ __forceinline__ void gload16(const u16* g, u16* l) {
  __builtin_amdgcn_global_load_lds(
      (const __attribute__((address_space(1))) unsigned int*)g,
      (__attribute__((address_space(3))) unsigned int*)l, 16, 0, 0);
}

// ---------- convert x (f32 -> bf16) ----------
__global__ void conv_x(const float* __restrict__ x, u16* __restrict__ oh) {
  size_t i = (size_t)blockIdx.x * 256 + threadIdx.x;
  f32x4 v = *(const f32x4*)(x + i * 4);
  u16x4v h;
#pragma unroll
  for (int j = 0; j < 4; ++j) h[j] = f2bf(v[j]);
  *(u16x4v*)(oh + i * 4) = h;
}

// ---------- transpose: W[K][N] f32 -> Wt[N][K] bf16 ----------
__global__ void conv_wT(const float* __restrict__ W, u16* __restrict__ Wt,
                        int Kd, int Nd) {
  __shared__ float t[32][33];
  int n0 = blockIdx.x * 32, k0 = blockIdx.y * 32;
  int c = threadIdx.x & 31, r8 = threadIdx.x >> 5;
#pragma unroll
  for (int rr = 0; rr < 32; rr += 8)
    t[r8 + rr][c] = W[(size_t)(k0 + r8 + rr) * Nd + n0 + c];
  __syncthreads();
#pragma unroll
  for (int rr = 0; rr < 32; rr += 8)
    Wt[(size_t)(n0 + r8 + rr) * Kd + k0 + c] = f2bf(t[c][r8 + rr]);
}

// ---------- combined QKV projection GEMM (single-term bf16) ----------
// B = [wqT | wkvT] rows: col<1024 -> Q (rope, pre-scaled by QSCALE),
// 1024..2047 -> K (rope), else V.
__global__ void __launch_bounds__(256, 3)
gemmQKV(const u16* __restrict__ Ah, const u16* __restrict__ Bt,
        u16* __restrict__ Qb, u16* __restrict__ Kb, u16* __restrict__ Vb,
        int M, int N, int K) {
  __shared__ u16 AsH[128][64];
  __shared__ u16 BsH[128][64];
  const int tid = threadIdx.x;
  const int lane = tid & 63, wave = tid >> 6;
  const int wr = wave >> 1, wc = wave & 1;
  const int lr = lane & 15, lg = lane >> 4;
  const int bm = blockIdx.y * 128, bn = blockIdx.x * 128;
  const int lrow = lane >> 3;
  const int lcol8 = (lane & 7) * 8;

  f32x4 acc[4][4];
#pragma unroll
  for (int m = 0; m < 4; ++m)
#pragma unroll
    for (int n = 0; n < 4; ++n) acc[m][n] = (f32x4){0.f, 0.f, 0.f, 0.f};

  for (int k0 = 0; k0 < K; k0 += 64) {
    __syncthreads();
#pragma unroll
    for (int c = 0; c < 4; ++c) {
      int r0 = wave * 32 + c * 8;
      size_t arow = (size_t)(bm + r0 + lrow) * K + k0 + lcol8;
      size_t brow = (size_t)(bn + r0 + lrow) * K + k0 + lcol8;
      gload16(Ah + arow, &AsH[r0][0]);
      gload16(Bt + brow, &BsH[r0][0]);
    }
    __syncthreads();
#pragma unroll
    for (int kk = 0; kk < 2; ++kk) {
      bf16x8 afh[4], bfh[4];
#pragma unroll
      for (int m = 0; m < 4; ++m)
        afh[m] = *(const bf16x8*)&AsH[wr * 64 + m * 16 + lr][kk * 32 + lg * 8];
#pragma unroll
      for (int n = 0; n < 4; ++n)
        bfh[n] = *(const bf16x8*)&BsH[wc * 64 + n * 16 + lr][kk * 32 + lg * 8];
#pragma unroll
      for (int m = 0; m < 4; ++m)
#pragma unroll
        for (int n = 0; n < 4; ++n)
          acc[m][n] = __builtin_amdgcn_mfma_f32_16x16x32_bf16(afh[m], bfh[n],
                                                              acc[m][n], 0, 0, 0);
    }
  }

  const int sel = bn >> 10;  // 0=Q, 1=K, 2=V
  u16* __restrict__ dst = sel == 0 ? Qb : (sel == 1 ? Kb : Vb);
  if (sel < 2) {  // fp32 RoPE on rotary dims
    float inv = __expf(-(float)lr * 0.5756462732485115f);
#pragma unroll
    for (int m = 0; m < 4; ++m) {
#pragma unroll
      for (int r = 0; r < 4; ++r) {
        int row = bm + wr * 64 + m * 16 + 4 * lg + r;
        int s = row & (SEQ - 1);
        float ang = (float)s * inv;
        float sn, cs;
        __sincosf(ang, &sn, &cs);
        float x1 = acc[m][0][r], x2 = acc[m][1][r];
        acc[m][0][r] = x1 * cs - x2 * sn;
        acc[m][1][r] = x2 * cs + x1 * sn;
      }
    }
  }
  const float oscale = sel == 0 ? QSCALE : 1.0f;

#pragma unroll
  for (int m = 0; m < 4; ++m) {
#pragma unroll
    for (int n = 0; n < 4; ++n) {
#pragma unroll
      for (int r = 0; r < 4; ++r) {
        int row = bm + wr * 64 + m * 16 + 4 * lg + r;
        int col = bn + wc * 64 + n * 16 + lr;
        int b = row >> 11, s = row & 2047;
        int h = (col >> 6) & 15, d = col & 63;
        dst[(((size_t)(b * NH + h)) * SEQ + s) * HD + d] =
            f2bf(acc[m][n][r] * oscale);
      }
    }
  }
}

// ---------- output projection GEMM, 128x64 tiles ----------
__global__ void __launch_bounds__(256, 2)
gemm1(const u16* __restrict__ A, const u16* __restrict__ Bt,
      float* __restrict__ CF, int M, int N, int K) {
  __shared__ u16 As[128][64];
  __shared__ u16 Bs[64][64];
  const int tid = threadIdx.x;
  const int lane = tid & 63, wave = tid >> 6;
  const int wr = wave >> 1, wc = wave & 1;
  const int lr = lane & 15, lg = lane >> 4;
  const int bm = blockIdx.y * 128, bn = blockIdx.x * 64;
  const int lrow = lane >> 3;
  const int lcol8 = (lane & 7) * 8;

  f32x4 acc[4][2];
#pragma unroll
  for (int m = 0; m < 4; ++m)
#pragma unroll
    for (int n = 0; n < 2; ++n) acc[m][n] = (f32x4){0.f, 0.f, 0.f, 0.f};

  for (int k0 = 0; k0 < K; k0 += 64) {
    __syncthreads();
#pragma unroll
    for (int c = 0; c < 4; ++c) {
      int r0 = wave * 32 + c * 8;
      gload16(A + (size_t)(bm + r0 + lrow) * K + k0 + lcol8, &As[r0][0]);
    }
#pragma unroll
    for (int c = 0; c < 2; ++c) {
      int r0 = wave * 16 + c * 8;
      gload16(Bt + (size_t)(bn + r0 + lrow) * K + k0 + lcol8, &Bs[r0][0]);
    }
    __syncthreads();
#pragma unroll
    for (int kk = 0; kk < 2; ++kk) {
      bf16x8 af[4], bfr[2];
#pragma unroll
      for (int m = 0; m < 4; ++m)
        af[m] = *(const bf16x8*)&As[wr * 64 + m * 16 + lr][kk * 32 + lg * 8];
#pragma unroll
      for (int n = 0; n < 2; ++n)
        bfr[n] = *(const bf16x8*)&Bs[wc * 32 + n * 16 + lr][kk * 32 + lg * 8];
#pragma unroll
      for (int m = 0; m < 4; ++m)
#pragma unroll
        for (int n = 0; n < 2; ++n)
          acc[m][n] = __builtin_amdgcn_mfma_f32_16x16x32_bf16(af[m], bfr[n],
                                                              acc[m][n], 0, 0, 0);
    }
  }

#pragma unroll
  for (int m = 0; m < 4; ++m)
#pragma unroll
    for (int n = 0; n < 2; ++n)
#pragma unroll
      for (int r = 0; r < 4; ++r) {
        int row = bm + wr * 64 + m * 16 + 4 * lg + r;
        int col = bn + wc * 32 + n * 16 + lr;
        CF[(size_t)row * N + col] = acc[m][n][r];
      }
}

// ---------- flash attention: 32x32 swapped-QK^T, base-2 softmax -------------
// R15 structure; tree-reduced row max/sum (depth 5 instead of serial 31/32).
__global__ void __launch_bounds__(256, 2)
attn_kernel(const u16* __restrict__ Q, const u16* __restrict__ K,
            const u16* __restrict__ V, float* __restrict__ Op0,
            float* __restrict__ Op1, float* __restrict__ ml) {
  __shared__ u16 Ks[64][72];
  __shared__ u16 Vt[64][72];  // Vt[d][kv]
  const int tid = threadIdx.x, lane = tid & 63, wave = tid >> 6;
  const int hi = lane >> 5, l31 = lane & 31;
  const int bx = blockIdx.x, bh = blockIdx.y;
  const size_t kvbase = (size_t)bh * SEQ * HD;
  const int HS = 32 * SEQ;
  const int kr0 = tid >> 3, kc0 = (tid & 7) * 8;
  const int vr = tid & 63;
  const int vc0A = (tid >> 6) * 8, vc0B = vc0A + 32;

  u16x8v kreg0, kreg1, vreg0, vreg1;

#pragma unroll 1
  for (int phase = 0; phase < 2; ++phase) {
    const int qt = phase ? 15 - bx : bx;
    const int g = phase;              // kv-half handled this phase
    const int nper = qt + 1;          // tiles in this half
    const int ktbegin = g * nper;
    const int qrow = qt * 128 + wave * 32 + l31;
    float* __restrict__ Opart = g ? Op1 : Op0;

    const u16* qp = Q + kvbase + (size_t)qrow * HD + 8 * hi;
    bf16x8 qf0 = *(const bf16x8*)(qp);
    bf16x8 qf1 = *(const bf16x8*)(qp + 16);
    bf16x8 qf2 = *(const bf16x8*)(qp + 32);
    bf16x8 qf3 = *(const bf16x8*)(qp + 48);

    f32x16 o0 = {0.f}, o1 = {0.f};
    float m = -1e30f, l = 0.f;

    {
      const u16* kp = K + kvbase + (size_t)(ktbegin * 64) * HD;
      const u16* vp = V + kvbase + (size_t)(ktbegin * 64) * HD;
      kreg0 = *(const u16x8v*)(kp + (size_t)kr0 * HD + kc0);
      kreg1 = *(const u16x8v*)(kp + (size_t)(kr0 + 32) * HD + kc0);
      vreg0 = *(const u16x8v*)(vp + (size_t)vr * HD + vc0A);
      vreg1 = *(const u16x8v*)(vp + (size_t)vr * HD + vc0B);
    }

#pragma unroll 1
    for (int i = 0; i < nper; ++i) {
      const int kt = ktbegin + i;
      __syncthreads();
      *(u16x8v*)&Ks[kr0][kc0] = kreg0;
      *(u16x8v*)&Ks[kr0 + 32][kc0] = kreg1;
#pragma unroll
      for (int j = 0; j < 8; ++j) Vt[vc0A + j][vr] = vreg0[j];
#pragma unroll
      for (int j = 0; j < 8; ++j) Vt[vc0B + j][vr] = vreg1[j];
      __syncthreads();
      if (i + 1 < nper) {
        const u16* kp = K + kvbase + (size_t)((kt + 1) * 64) * HD;
        const u16* vp = V + kvbase + (size_t)((kt + 1) * 64) * HD;
        kreg0 = *(const u16x8v*)(kp + (size_t)kr0 * HD + kc0);
        kreg1 = *(const u16x8v*)(kp + (size_t)(kr0 + 32) * HD + kc0);
        vreg0 = *(const u16x8v*)(vp + (size_t)vr * HD + vc0A);
        vreg1 = *(const u16x8v*)(vp + (size_t)vr * HD + vc0B);
      }

      f32x16 s0 = {0.f}, s1 = {0.f};
      __builtin_amdgcn_s_setprio(1);
#pragma unroll
      for (int kk = 0; kk < 4; ++kk) {
        bf16x8 qk = kk == 0 ? qf0 : (kk == 1 ? qf1 : (kk == 2 ? qf2 : qf3));
        bf16x8 af0 = *(const bf16x8*)&Ks[l31][16 * kk + 8 * hi];
        bf16x8 af1 = *(const bf16x8*)&Ks[32 + l31][16 * kk + 8 * hi];
        s0 = __builtin_amdgcn_mfma_f32_32x32x16_bf16(af0, qk, s0, 0, 0, 0);
        s1 = __builtin_amdgcn_mfma_f32_32x32x16_bf16(af1, qk, s1, 0, 0, 0);
      }
      __builtin_amdgcn_s_setprio(0);
      // no scaling: Q was pre-scaled; S already in log2 domain

      if (kt >= 2 * qt) {  // diagonal tiles: mask kv > q
#pragma unroll
        for (int r = 0; r < 16; ++r) {
          int rowi = (r & 3) + 8 * (r >> 2) + 4 * hi;
          if (kt * 64 + rowi > qrow) s0[r] = -1e30f;
          if (kt * 64 + 32 + rowi > qrow) s1[r] = -1e30f;
        }
      }

      // tree-reduced row max (depth 5)
      float t16[16];
#pragma unroll
      for (int r = 0; r < 16; ++r) t16[r] = fmaxf(s0[r], s1[r]);
#pragma unroll
      for (int r = 0; r < 8; ++r) t16[r] = fmaxf(t16[r], t16[r + 8]);
#pragma unroll
      for (int r = 0; r < 4; ++r) t16[r] = fmaxf(t16[r], t16[r + 4]);
      float mx = fmaxf(fmaxf(t16[0], t16[1]), fmaxf(t16[2], t16[3]));
      mx = fmaxf(mx, __shfl_xor(mx, 32));

      bool defer = __all(mx - m <= DEFER_THR);
      if (!defer) {
        float mn = fmaxf(m, mx);
        float fac = exp2f(m - mn);
        m = mn;
        l *= fac;
        o0 *= fac;
        o1 *= fac;
      }
#pragma unroll
      for (int r = 0; r < 16; ++r) s0[r] = exp2f(s0[r] - m);
#pragma unroll
      for (int r = 0; r < 16; ++r) s1[r] = exp2f(s1[r] - m);
      // tree-reduced row sum (depth 5)
      float u16a[16];
#pragma unroll
      for (int r = 0; r < 16; ++r) u16a[r] = s0[r] + s1[r];
#pragma unroll
      for (int r = 0; r < 8; ++r) u16a[r] += u16a[r + 8];
#pragma unroll
      for (int r = 0; r < 4; ++r) u16a[r] += u16a[r + 4];
      float rsum = (u16a[0] + u16a[1]) + (u16a[2] + u16a[3]);
      rsum += __shfl_xor(rsum, 32);
      l += rsum;

      u32 P0a[4], P1a[4], P0b[4], P1b[4];
#pragma unroll
      for (int gg = 0; gg < 4; ++gg) {
        P0a[gg] = cvtpk(s0[4 * gg], s0[4 * gg + 1]);
        P1a[gg] = cvtpk(s0[4 * gg + 2], s0[4 * gg + 3]);
        P0b[gg] = cvtpk(s1[4 * gg], s1[4 * gg + 1]);
        P1b[gg] = cvtpk(s1[4 * gg + 2], s1[4 * gg + 3]);
      }

      __builtin_amdgcn_s_setprio(1);
#pragma unroll
      for (int c = 0; c < 4; ++c) {
        const int gA = 2 * (c & 1);
        u32 p0lo, p0hi, p1lo, p1hi;
        if (c < 2) {
          p0lo = P0a[gA];
          p0hi = P0a[gA + 1];
          p1lo = P1a[gA];
          p1hi = P1a[gA + 1];
        } else {
          p0lo = P0b[gA];
          p0hi = P0b[gA + 1];
          p1lo = P1b[gA];
          p1hi = P1b[gA + 1];
        }
        u32 send0 = hi ? p0lo : p0hi;
        u32 send1 = hi ? p1lo : p1hi;
        u32 recv0 = (u32)__shfl_xor((int)send0, 32);
        u32 recv1 = (u32)__shfl_xor((int)send1, 32);
        u32 own0 = hi ? p0hi : p0lo;
        u32 own1 = hi ? p1hi : p1lo;
        u32x4 bw;
        bw[0] = hi ? recv0 : own0;
        bw[1] = hi ? recv1 : own1;
        bw[2] = hi ? own0 : recv0;
        bw[3] = hi ? own1 : recv1;
        bf16x8 bfrag = __builtin_bit_cast(bf16x8, bw);
        bf16x8 av0 = *(const bf16x8*)&Vt[l31][16 * c + 8 * hi];
        bf16x8 av1 = *(const bf16x8*)&Vt[32 + l31][16 * c + 8 * hi];
        o0 = __builtin_amdgcn_mfma_f32_32x32x16_bf16(av0, bfrag, o0, 0, 0, 0);
        o1 = __builtin_amdgcn_mfma_f32_32x32x16_bf16(av1, bfrag, o1, 0, 0, 0);
      }
      __builtin_amdgcn_s_setprio(0);
    }

    // epilogue: premultiplied O^T partial -> Opart[bh][s][d] (f32), m/l
    {
      size_t base = ((size_t)bh * SEQ + qrow) * HD;
#pragma unroll
      for (int gg = 0; gg < 4; ++gg) {
        f32x4 v0 = {o0[4 * gg], o0[4 * gg + 1], o0[4 * gg + 2], o0[4 * gg + 3]};
        f32x4 v1 = {o1[4 * gg], o1[4 * gg + 1], o1[4 * gg + 2], o1[4 * gg + 3]};
        *(f32x4*)(Opart + base + 8 * gg + 4 * hi) = v0;
        *(f32x4*)(Opart + base + 32 + 8 * gg + 4 * hi) = v1;
      }
      if (hi == 0) {
        ml[g * HS + bh * SEQ + qrow] = m;
        ml[2 * HS + g * HS + bh * SEQ + qrow] = l;
      }
    }
    __syncthreads();  // protect LDS before next phase's staging
  }
}

// ---------- merge the two KV-half partials, write bf16 O [b,s,h*64+d] -------
// m values are in log2 domain -> exp2f weights.
__global__ void merge_kernel(const float* __restrict__ Op0,
                             const float* __restrict__ Op1,
                             const float* __restrict__ ml,
                             u16* __restrict__ O) {
  int i = blockIdx.x * 256 + threadIdx.x;
  int row = i >> 4;  // bh*SEQ + s
  int d0 = (i & 15) * 4;
  size_t base = (size_t)row * 64 + d0;
  f32x4 o1 = *(const f32x4*)(Op0 + base);
  f32x4 o2 = *(const f32x4*)(Op1 + base);
  const int HS = 32 * SEQ;
  float m1 = ml[row], m2 = ml[HS + row];
  float l1 = ml[2 * HS + row], l2 = ml[3 * HS + row];
  float M = fmaxf(m1, m2);
  float w1 = exp2f(m1 - M), w2 = exp2f(m2 - M);
  float inv = 1.0f / (l1 * w1 + l2 * w2);
  int bh = row >> 11, s = row & 2047;
  int b = bh >> 4, h = bh & 15;
  u16x4v rr;
#pragma unroll
  for (int j = 0; j < 4; ++j) rr[j] = f2bf((o1[j] * w1 + o2[j] * w2) * inv);
  *(u16x4v*)(O + ((size_t)(b * SEQ + s)) * DIMM + h * HD + d0) = rr;
}

extern "C" void kernel_launch(void* const* d_in, const int* in_sizes, int n_in,
                              void* d_out, int out_size, void* d_ws, size_t ws_size,
                              hipStream_t stream) {
  const float* x = (const float*)d_in[0];
  const float* wq = (const float*)d_in[1];
  const float* wkv = (const float*)d_in[2];
  const float* wout = (const float*)d_in[3];
  float* out = (float*)d_out;

  u16* ws = (u16*)d_ws;
  const size_t M1 = (size_t)1024 * 1024;
  u16* xh = ws;                    // 4M u16 (xl slab reserved for Op1 overlay)
  u16* xl = xh + 4 * M1;           // 4M (part of Op1 region)
  u16* wqTh = xl + 4 * M1;         // 1M  (wkvTh contiguous -> B[3072][1024])
  u16* wkvTh = wqTh + M1;          // 2M
  u16* Qb = wkvTh + 2 * M1;        // 4M
  u16* Kb = Qb + 4 * M1;           // 4M
  u16* Vb = Kb + 4 * M1;           // 4M
  // overlays:
  float* Op0 = out;                // d_out as scratch: 16MB
  float* Op1 = (float*)xh;         // xh+xl = 16MB (x dead after gemmQKV)
  float* mlbuf = (float*)wqTh;     // 1MB need; 2MB slab
  u16* Ob = Qb;                    // 8MB need; Qb dead after attn
  u16* woutT = Kb;                 // 2MB need; Kb dead after attn

  conv_x<<<4096, 256, 0, stream>>>(x, xh);
  conv_wT<<<dim3(32, 32), 256, 0, stream>>>(wq, wqTh, 1024, 1024);
  conv_wT<<<dim3(64, 32), 256, 0, stream>>>(wkv, wkvTh, 1024, 2048);

  gemmQKV<<<dim3(24, 32), 256, 0, stream>>>(xh, wqTh, Qb, Kb, Vb,
                                            4096, 3072, 1024);

  attn_kernel<<<dim3(16, 32), 256, 0, stream>>>(Qb, Kb, Vb, Op0, Op1, mlbuf);
  merge_kernel<<<4096, 256, 0, stream>>>(Op0, Op1, mlbuf, Ob);

  conv_wT<<<dim3(32, 32), 256, 0, stream>>>(wout, woutT, 1024, 1024);
  gemm1<<<dim3(16, 32), 256, 0, stream>>>(Ob, woutT, out, 4096, 1024, 1024);
}

// Round 26
// 123.581 us; speedup vs baseline: 1.0189x; 1.0189x over previous
//
#include <hip/hip_runtime.h>

typedef unsigned short u16;
typedef unsigned int u32;
typedef __bf16 bf16x8 __attribute__((ext_vector_type(8)));
typedef unsigned short u16x8v __attribute__((ext_vector_type(8)));
typedef unsigned short u16x4v __attribute__((ext_vector_type(4)));
typedef unsigned int u32x4 __attribute__((ext_vector_type(4)));
typedef float f32x4 __attribute__((ext_vector_type(4)));
typedef float f32x16 __attribute__((ext_vector_type(16)));

#define SEQ 2048
#define NH 16
#define HD 64
#define DIMM 1024
// softmax scale folded into Q: 1/sqrt(64) * log2(e)
#define QSCALE 0.18033688f
// defer-max threshold in log2 units (= 8 nats)
#define DEFER_THR 11.5417f

__device__ __forceinline__ u16 f2bf(float f) {
  unsigned u = __builtin_bit_cast(unsigned, f);
  u += 0x7fffu + ((u >> 16) & 1u);
  return (u16)(u >> 16);
}
__device__ __forceinline__ float bf2f(u16 b) {
  return __builtin_bit_cast(float, ((unsigned)b) << 16);
}
// RTNE pack of two f32 -> packed bf16 pair, single HW instruction
__device__ __forceinline__ u32 cvtpk(float a, float b) {
  u32 r;
  asm("v_cvt_pk_bf16_f32 %0, %1, %2" : "=v"(r) : "v"(a), "v"(b));
  return r;
}

// async global->LDS, 16B per lane; LDS dest = wave-uniform base + lane*16
__device__ __forceinline__ void gload16(const u16* g, u16* l) {
  __builtin_amdgcn_global_load_lds(
      (const __attribute__((address_space(1))) unsigned int*)g,
      (__attribute__((address_space(3))) unsigned int*)l, 16, 0, 0);
}

// ---------- convert x (f32 -> bf16) ----------
__global__ void conv_x(const float* __restrict__ x, u16* __restrict__ oh) {
  size_t i = (size_t)blockIdx.x * 256 + threadIdx.x;
  f32x4 v = *(const f32x4*)(x + i * 4);
  u16x4v h;
#pragma unroll
  for (int j = 0; j < 4; ++j) h[j] = f2bf(v[j]);
  *(u16x4v*)(oh + i * 4) = h;
}

// ---------- transpose: W[K][N] f32 -> Wt[N][K] bf16 ----------
__global__ void conv_wT(const float* __restrict__ W, u16* __restrict__ Wt,
                        int Kd, int Nd) {
  __shared__ float t[32][33];
  int n0 = blockIdx.x * 32, k0 = blockIdx.y * 32;
  int c = threadIdx.x & 31, r8 = threadIdx.x >> 5;
#pragma unroll
  for (int rr = 0; rr < 32; rr += 8)
    t[r8 + rr][c] = W[(size_t)(k0 + r8 + rr) * Nd + n0 + c];
  __syncthreads();
#pragma unroll
  for (int rr = 0; rr < 32; rr += 8)
    Wt[(size_t)(n0 + r8 + rr) * Kd + k0 + c] = f2bf(t[c][r8 + rr]);
}

// ---------- combined QKV projection GEMM (single-term bf16) ----------
// B = [wqT | wkvT] rows: col<1024 -> Q (rope, pre-scaled by QSCALE),
// 1024..2047 -> K (rope), else V.
__global__ void __launch_bounds__(256, 3)
gemmQKV(const u16* __restrict__ Ah, const u16* __restrict__ Bt,
        u16* __restrict__ Qb, u16* __restrict__ Kb, u16* __restrict__ Vb,
        int M, int N, int K) {
  __shared__ u16 AsH[128][64];
  __shared__ u16 BsH[128][64];
  const int tid = threadIdx.x;
  const int lane = tid & 63, wave = tid >> 6;
  const int wr = wave >> 1, wc = wave & 1;
  const int lr = lane & 15, lg = lane >> 4;
  const int bm = blockIdx.y * 128, bn = blockIdx.x * 128;
  const int lrow = lane >> 3;
  const int lcol8 = (lane & 7) * 8;

  f32x4 acc[4][4];
#pragma unroll
  for (int m = 0; m < 4; ++m)
#pragma unroll
    for (int n = 0; n < 4; ++n) acc[m][n] = (f32x4){0.f, 0.f, 0.f, 0.f};

  for (int k0 = 0; k0 < K; k0 += 64) {
    __syncthreads();
#pragma unroll
    for (int c = 0; c < 4; ++c) {
      int r0 = wave * 32 + c * 8;
      size_t arow = (size_t)(bm + r0 + lrow) * K + k0 + lcol8;
      size_t brow = (size_t)(bn + r0 + lrow) * K + k0 + lcol8;
      gload16(Ah + arow, &AsH[r0][0]);
      gload16(Bt + brow, &BsH[r0][0]);
    }
    __syncthreads();
#pragma unroll
    for (int kk = 0; kk < 2; ++kk) {
      bf16x8 afh[4], bfh[4];
#pragma unroll
      for (int m = 0; m < 4; ++m)
        afh[m] = *(const bf16x8*)&AsH[wr * 64 + m * 16 + lr][kk * 32 + lg * 8];
#pragma unroll
      for (int n = 0; n < 4; ++n)
        bfh[n] = *(const bf16x8*)&BsH[wc * 64 + n * 16 + lr][kk * 32 + lg * 8];
#pragma unroll
      for (int m = 0; m < 4; ++m)
#pragma unroll
        for (int n = 0; n < 4; ++n)
          acc[m][n] = __builtin_amdgcn_mfma_f32_16x16x32_bf16(afh[m], bfh[n],
                                                              acc[m][n], 0, 0, 0);
    }
  }

  const int sel = bn >> 10;  // 0=Q, 1=K, 2=V
  u16* __restrict__ dst = sel == 0 ? Qb : (sel == 1 ? Kb : Vb);
  if (sel < 2) {  // fp32 RoPE on rotary dims
    float inv = __expf(-(float)lr * 0.5756462732485115f);
#pragma unroll
    for (int m = 0; m < 4; ++m) {
#pragma unroll
      for (int r = 0; r < 4; ++r) {
        int row = bm + wr * 64 + m * 16 + 4 * lg + r;
        int s = row & (SEQ - 1);
        float ang = (float)s * inv;
        float sn, cs;
        __sincosf(ang, &sn, &cs);
        float x1 = acc[m][0][r], x2 = acc[m][1][r];
        acc[m][0][r] = x1 * cs - x2 * sn;
        acc[m][1][r] = x2 * cs + x1 * sn;
      }
    }
  }
  const float oscale = sel == 0 ? QSCALE : 1.0f;

#pragma unroll
  for (int m = 0; m < 4; ++m) {
#pragma unroll
    for (int n = 0; n < 4; ++n) {
#pragma unroll
      for (int r = 0; r < 4; ++r) {
        int row = bm + wr * 64 + m * 16 + 4 * lg + r;
        int col = bn + wc * 64 + n * 16 + lr;
        int b = row >> 11, s = row & 2047;
        int h = (col >> 6) & 15, d = col & 63;
        dst[(((size_t)(b * NH + h)) * SEQ + s) * HD + d] =
            f2bf(acc[m][n][r] * oscale);
      }
    }
  }
}

// ---------- output projection GEMM, 128x64 tiles ----------
__global__ void __launch_bounds__(256, 2)
gemm1(const u16* __restrict__ A, const u16* __restrict__ Bt,
      float* __restrict__ CF, int M, int N, int K) {
  __shared__ u16 As[128][64];
  __shared__ u16 Bs[64][64];
  const int tid = threadIdx.x;
  const int lane = tid & 63, wave = tid >> 6;
  const int wr = wave >> 1, wc = wave & 1;
  const int lr = lane & 15, lg = lane >> 4;
  const int bm = blockIdx.y * 128, bn = blockIdx.x * 64;
  const int lrow = lane >> 3;
  const int lcol8 = (lane & 7) * 8;

  f32x4 acc[4][2];
#pragma unroll
  for (int m = 0; m < 4; ++m)
#pragma unroll
    for (int n = 0; n < 2; ++n) acc[m][n] = (f32x4){0.f, 0.f, 0.f, 0.f};

  for (int k0 = 0; k0 < K; k0 += 64) {
    __syncthreads();
#pragma unroll
    for (int c = 0; c < 4; ++c) {
      int r0 = wave * 32 + c * 8;
      gload16(A + (size_t)(bm + r0 + lrow) * K + k0 + lcol8, &As[r0][0]);
    }
#pragma unroll
    for (int c = 0; c < 2; ++c) {
      int r0 = wave * 16 + c * 8;
      gload16(Bt + (size_t)(bn + r0 + lrow) * K + k0 + lcol8, &Bs[r0][0]);
    }
    __syncthreads();
#pragma unroll
    for (int kk = 0; kk < 2; ++kk) {
      bf16x8 af[4], bfr[2];
#pragma unroll
      for (int m = 0; m < 4; ++m)
        af[m] = *(const bf16x8*)&As[wr * 64 + m * 16 + lr][kk * 32 + lg * 8];
#pragma unroll
      for (int n = 0; n < 2; ++n)
        bfr[n] = *(const bf16x8*)&Bs[wc * 32 + n * 16 + lr][kk * 32 + lg * 8];
#pragma unroll
      for (int m = 0; m < 4; ++m)
#pragma unroll
        for (int n = 0; n < 2; ++n)
          acc[m][n] = __builtin_amdgcn_mfma_f32_16x16x32_bf16(af[m], bfr[n],
                                                              acc[m][n], 0, 0, 0);
    }
  }

#pragma unroll
  for (int m = 0; m < 4; ++m)
#pragma unroll
    for (int n = 0; n < 2; ++n)
#pragma unroll
      for (int r = 0; r < 4; ++r) {
        int row = bm + wr * 64 + m * 16 + 4 * lg + r;
        int col = bn + wc * 32 + n * 16 + lr;
        CF[(size_t)row * N + col] = acc[m][n][r];
      }
}

// ---------- flash attention: 32x32 swapped-QK^T, base-2 softmax -------------
// R15 structure; Q pre-scaled by QSCALE so S is in log2 domain: P = exp2(S-m).
__global__ void __launch_bounds__(256, 2)
attn_kernel(const u16* __restrict__ Q, const u16* __restrict__ K,
            const u16* __restrict__ V, float* __restrict__ Op0,
            float* __restrict__ Op1, float* __restrict__ ml) {
  __shared__ u16 Ks[64][72];
  __shared__ u16 Vt[64][72];  // Vt[d][kv]
  const int tid = threadIdx.x, lane = tid & 63, wave = tid >> 6;
  const int hi = lane >> 5, l31 = lane & 31;
  const int bx = blockIdx.x, bh = blockIdx.y;
  const size_t kvbase = (size_t)bh * SEQ * HD;
  const int HS = 32 * SEQ;
  const int kr0 = tid >> 3, kc0 = (tid & 7) * 8;
  const int vr = tid & 63;
  const int vc0A = (tid >> 6) * 8, vc0B = vc0A + 32;

  u16x8v kreg0, kreg1, vreg0, vreg1;

#pragma unroll 1
  for (int phase = 0; phase < 2; ++phase) {
    const int qt = phase ? 15 - bx : bx;
    const int g = phase;              // kv-half handled this phase
    const int nper = qt + 1;          // tiles in this half
    const int ktbegin = g * nper;
    const int qrow = qt * 128 + wave * 32 + l31;
    float* __restrict__ Opart = g ? Op1 : Op0;

    const u16* qp = Q + kvbase + (size_t)qrow * HD + 8 * hi;
    bf16x8 qf0 = *(const bf16x8*)(qp);
    bf16x8 qf1 = *(const bf16x8*)(qp + 16);
    bf16x8 qf2 = *(const bf16x8*)(qp + 32);
    bf16x8 qf3 = *(const bf16x8*)(qp + 48);

    f32x16 o0 = {0.f}, o1 = {0.f};
    float m = -1e30f, l = 0.f;

    {
      const u16* kp = K + kvbase + (size_t)(ktbegin * 64) * HD;
      const u16* vp = V + kvbase + (size_t)(ktbegin * 64) * HD;
      kreg0 = *(const u16x8v*)(kp + (size_t)kr0 * HD + kc0);
      kreg1 = *(const u16x8v*)(kp + (size_t)(kr0 + 32) * HD + kc0);
      vreg0 = *(const u16x8v*)(vp + (size_t)vr * HD + vc0A);
      vreg1 = *(const u16x8v*)(vp + (size_t)vr * HD + vc0B);
    }

#pragma unroll 1
    for (int i = 0; i < nper; ++i) {
      const int kt = ktbegin + i;
      __syncthreads();
      *(u16x8v*)&Ks[kr0][kc0] = kreg0;
      *(u16x8v*)&Ks[kr0 + 32][kc0] = kreg1;
#pragma unroll
      for (int j = 0; j < 8; ++j) Vt[vc0A + j][vr] = vreg0[j];
#pragma unroll
      for (int j = 0; j < 8; ++j) Vt[vc0B + j][vr] = vreg1[j];
      __syncthreads();
      if (i + 1 < nper) {
        const u16* kp = K + kvbase + (size_t)((kt + 1) * 64) * HD;
        const u16* vp = V + kvbase + (size_t)((kt + 1) * 64) * HD;
        kreg0 = *(const u16x8v*)(kp + (size_t)kr0 * HD + kc0);
        kreg1 = *(const u16x8v*)(kp + (size_t)(kr0 + 32) * HD + kc0);
        vreg0 = *(const u16x8v*)(vp + (size_t)vr * HD + vc0A);
        vreg1 = *(const u16x8v*)(vp + (size_t)vr * HD + vc0B);
      }

      f32x16 s0 = {0.f}, s1 = {0.f};
      __builtin_amdgcn_s_setprio(1);
#pragma unroll
      for (int kk = 0; kk < 4; ++kk) {
        bf16x8 qk = kk == 0 ? qf0 : (kk == 1 ? qf1 : (kk == 2 ? qf2 : qf3));
        bf16x8 af0 = *(const bf16x8*)&Ks[l31][16 * kk + 8 * hi];
        bf16x8 af1 = *(const bf16x8*)&Ks[32 + l31][16 * kk + 8 * hi];
        s0 = __builtin_amdgcn_mfma_f32_32x32x16_bf16(af0, qk, s0, 0, 0, 0);
        s1 = __builtin_amdgcn_mfma_f32_32x32x16_bf16(af1, qk, s1, 0, 0, 0);
      }
      __builtin_amdgcn_s_setprio(0);
      // no scaling: Q was pre-scaled; S already in log2 domain

      if (kt >= 2 * qt) {  // diagonal tiles: mask kv > q
#pragma unroll
        for (int r = 0; r < 16; ++r) {
          int rowi = (r & 3) + 8 * (r >> 2) + 4 * hi;
          if (kt * 64 + rowi > qrow) s0[r] = -1e30f;
          if (kt * 64 + 32 + rowi > qrow) s1[r] = -1e30f;
        }
      }

      float mx = s0[0];
#pragma unroll
      for (int r = 1; r < 16; ++r) mx = fmaxf(mx, s0[r]);
#pragma unroll
      for (int r = 0; r < 16; ++r) mx = fmaxf(mx, s1[r]);
      mx = fmaxf(mx, __shfl_xor(mx, 32));

      bool defer = __all(mx - m <= DEFER_THR);
      if (!defer) {
        float mn = fmaxf(m, mx);
        float fac = exp2f(m - mn);
        m = mn;
        l *= fac;
        o0 *= fac;
        o1 *= fac;
      }
      float rsum = 0.f;
#pragma unroll
      for (int r = 0; r < 16; ++r) {
        s0[r] = exp2f(s0[r] - m);
        rsum += s0[r];
      }
#pragma unroll
      for (int r = 0; r < 16; ++r) {
        s1[r] = exp2f(s1[r] - m);
        rsum += s1[r];
      }
      rsum += __shfl_xor(rsum, 32);
      l += rsum;

      u32 P0a[4], P1a[4], P0b[4], P1b[4];
#pragma unroll
      for (int gg = 0; gg < 4; ++gg) {
        P0a[gg] = cvtpk(s0[4 * gg], s0[4 * gg + 1]);
        P1a[gg] = cvtpk(s0[4 * gg + 2], s0[4 * gg + 3]);
        P0b[gg] = cvtpk(s1[4 * gg], s1[4 * gg + 1]);
        P1b[gg] = cvtpk(s1[4 * gg + 2], s1[4 * gg + 3]);
      }

      __builtin_amdgcn_s_setprio(1);
#pragma unroll
      for (int c = 0; c < 4; ++c) {
        const int gA = 2 * (c & 1);
        u32 p0lo, p0hi, p1lo, p1hi;
        if (c < 2) {
          p0lo = P0a[gA];
          p0hi = P0a[gA + 1];
          p1lo = P1a[gA];
          p1hi = P1a[gA + 1];
        } else {
          p0lo = P0b[gA];
          p0hi = P0b[gA + 1];
          p1lo = P1b[gA];
          p1hi = P1b[gA + 1];
        }
        u32 send0 = hi ? p0lo : p0hi;
        u32 send1 = hi ? p1lo : p1hi;
        u32 recv0 = (u32)__shfl_xor((int)send0, 32);
        u32 recv1 = (u32)__shfl_xor((int)send1, 32);
        u32 own0 = hi ? p0hi : p0lo;
        u32 own1 = hi ? p1hi : p1lo;
        u32x4 bw;
        bw[0] = hi ? recv0 : own0;
        bw[1] = hi ? recv1 : own1;
        bw[2] = hi ? own0 : recv0;
        bw[3] = hi ? own1 : recv1;
        bf16x8 bfrag = __builtin_bit_cast(bf16x8, bw);
        bf16x8 av0 = *(const bf16x8*)&Vt[l31][16 * c + 8 * hi];
        bf16x8 av1 = *(const bf16x8*)&Vt[32 + l31][16 * c + 8 * hi];
        o0 = __builtin_amdgcn_mfma_f32_32x32x16_bf16(av0, bfrag, o0, 0, 0, 0);
        o1 = __builtin_amdgcn_mfma_f32_32x32x16_bf16(av1, bfrag, o1, 0, 0, 0);
      }
      __builtin_amdgcn_s_setprio(0);
    }

    // epilogue: premultiplied O^T partial -> Opart[bh][s][d] (f32), m/l
    {
      size_t base = ((size_t)bh * SEQ + qrow) * HD;
#pragma unroll
      for (int gg = 0; gg < 4; ++gg) {
        f32x4 v0 = {o0[4 * gg], o0[4 * gg + 1], o0[4 * gg + 2], o0[4 * gg + 3]};
        f32x4 v1 = {o1[4 * gg], o1[4 * gg + 1], o1[4 * gg + 2], o1[4 * gg + 3]};
        *(f32x4*)(Opart + base + 8 * gg + 4 * hi) = v0;
        *(f32x4*)(Opart + base + 32 + 8 * gg + 4 * hi) = v1;
      }
      if (hi == 0) {
        ml[g * HS + bh * SEQ + qrow] = m;
        ml[2 * HS + g * HS + bh * SEQ + qrow] = l;
      }
    }
    __syncthreads();  // protect LDS before next phase's staging
  }
}

// ---------- merge the two KV-half partials, write bf16 O [b,s,h*64+d] -------
// m values are in log2 domain -> exp2f weights.
__global__ void merge_kernel(const float* __restrict__ Op0,
                             const float* __restrict__ Op1,
                             const float* __restrict__ ml,
                             u16* __restrict__ O) {
  int i = blockIdx.x * 256 + threadIdx.x;
  int row = i >> 4;  // bh*SEQ + s
  int d0 = (i & 15) * 4;
  size_t base = (size_t)row * 64 + d0;
  f32x4 o1 = *(const f32x4*)(Op0 + base);
  f32x4 o2 = *(const f32x4*)(Op1 + base);
  const int HS = 32 * SEQ;
  float m1 = ml[row], m2 = ml[HS + row];
  float l1 = ml[2 * HS + row], l2 = ml[3 * HS + row];
  float M = fmaxf(m1, m2);
  float w1 = exp2f(m1 - M), w2 = exp2f(m2 - M);
  float inv = 1.0f / (l1 * w1 + l2 * w2);
  int bh = row >> 11, s = row & 2047;
  int b = bh >> 4, h = bh & 15;
  u16x4v rr;
#pragma unroll
  for (int j = 0; j < 4; ++j) rr[j] = f2bf((o1[j] * w1 + o2[j] * w2) * inv);
  *(u16x4v*)(O + ((size_t)(b * SEQ + s)) * DIMM + h * HD + d0) = rr;
}

extern "C" void kernel_launch(void* const* d_in, const int* in_sizes, int n_in,
                              void* d_out, int out_size, void* d_ws, size_t ws_size,
                              hipStream_t stream) {
  const float* x = (const float*)d_in[0];
  const float* wq = (const float*)d_in[1];
  const float* wkv = (const float*)d_in[2];
  const float* wout = (const float*)d_in[3];
  float* out = (float*)d_out;

  u16* ws = (u16*)d_ws;
  const size_t M1 = (size_t)1024 * 1024;
  u16* xh = ws;                    // 4M u16 (xl slab reserved for Op1 overlay)
  u16* xl = xh + 4 * M1;           // 4M (part of Op1 region)
  u16* wqTh = xl + 4 * M1;         // 1M  (wkvTh contiguous -> B[3072][1024])
  u16* wkvTh = wqTh + M1;          // 2M
  u16* Qb = wkvTh + 2 * M1;        // 4M
  u16* Kb = Qb + 4 * M1;           // 4M
  u16* Vb = Kb + 4 * M1;           // 4M
  // overlays:
  float* Op0 = out;                // d_out as scratch: 16MB
  float* Op1 = (float*)xh;         // xh+xl = 16MB (x dead after gemmQKV)
  float* mlbuf = (float*)wqTh;     // 1MB need; 2MB slab
  u16* Ob = Qb;                    // 8MB need; Qb dead after attn
  u16* woutT = Kb;                 // 2MB need; Kb dead after attn

  conv_x<<<4096, 256, 0, stream>>>(x, xh);
  conv_wT<<<dim3(32, 32), 256, 0, stream>>>(wq, wqTh, 1024, 1024);
  conv_wT<<<dim3(64, 32), 256, 0, stream>>>(wkv, wkvTh, 1024, 2048);

  gemmQKV<<<dim3(24, 32), 256, 0, stream>>>(xh, wqTh, Qb, Kb, Vb,
                                            4096, 3072, 1024);

  attn_kernel<<<dim3(16, 32), 256, 0, stream>>>(Qb, Kb, Vb, Op0, Op1, mlbuf);
  merge_kernel<<<4096, 256, 0, stream>>>(Op0, Op1, mlbuf, Ob);

  conv_wT<<<dim3(32, 32), 256, 0, stream>>>(wout, woutT, 1024, 1024);
  gemm1<<<dim3(16, 32), 256, 0, stream>>>(Ob, woutT, out, 4096, 1024, 1024);
}

// Round 27
// 121.455 us; speedup vs baseline: 1.0367x; 1.0175x over previous
//
#include <hip/hip_runtime.h>

typedef unsigned short u16;
typedef unsigned int u32;
typedef __bf16 bf16x8 __attribute__((ext_vector_type(8)));
typedef unsigned short u16x8v __attribute__((ext_vector_type(8)));
typedef unsigned short u16x4v __attribute__((ext_vector_type(4)));
typedef unsigned int u32x2 __attribute__((ext_vector_type(2)));
typedef unsigned int u32x4 __attribute__((ext_vector_type(4)));
typedef float f32x4 __attribute__((ext_vector_type(4)));
typedef float f32x16 __attribute__((ext_vector_type(16)));

#define SEQ 2048
#define NH 16
#define HD 64
#define DIMM 1024
// softmax scale folded into Q: 1/sqrt(64) * log2(e)
#define QSCALE 0.18033688f
// defer-max threshold in log2 units (= 8 nats)
#define DEFER_THR 11.5417f

__device__ __forceinline__ u16 f2bf(float f) {
  unsigned u = __builtin_bit_cast(unsigned, f);
  u += 0x7fffu + ((u >> 16) & 1u);
  return (u16)(u >> 16);
}
__device__ __forceinline__ float bf2f(u16 b) {
  return __builtin_bit_cast(float, ((unsigned)b) << 16);
}
// RTNE pack of two f32 -> packed bf16 pair, single HW instruction
__device__ __forceinline__ u32 cvtpk(float a, float b) {
  u32 r;
  asm("v_cvt_pk_bf16_f32 %0, %1, %2" : "=v"(r) : "v"(a), "v"(b));
  return r;
}

// async global->LDS, 16B per lane; LDS dest = wave-uniform base + lane*16
__device__ __forceinline__ void gload16(const u16* g, u16* l) {
  __builtin_amdgcn_global_load_lds(
      (const __attribute__((address_space(1))) unsigned int*)g,
      (__attribute__((address_space(3))) unsigned int*)l, 16, 0, 0);
}

// ---------- convert x (f32 -> bf16) ----------
__global__ void conv_x(const float* __restrict__ x, u16* __restrict__ oh) {
  size_t i = (size_t)blockIdx.x * 256 + threadIdx.x;
  f32x4 v = *(const f32x4*)(x + i * 4);
  u16x4v h;
#pragma unroll
  for (int j = 0; j < 4; ++j) h[j] = f2bf(v[j]);
  *(u16x4v*)(oh + i * 4) = h;
}

// ---------- transpose: W[K][N] f32 -> Wt[N][K] bf16 ----------
__global__ void conv_wT(const float* __restrict__ W, u16* __restrict__ Wt,
                        int Kd, int Nd) {
  __shared__ float t[32][33];
  int n0 = blockIdx.x * 32, k0 = blockIdx.y * 32;
  int c = threadIdx.x & 31, r8 = threadIdx.x >> 5;
#pragma unroll
  for (int rr = 0; rr < 32; rr += 8)
    t[r8 + rr][c] = W[(size_t)(k0 + r8 + rr) * Nd + n0 + c];
  __syncthreads();
#pragma unroll
  for (int rr = 0; rr < 32; rr += 8)
    Wt[(size_t)(n0 + r8 + rr) * Kd + k0 + c] = f2bf(t[c][r8 + rr]);
}

// ---------- combined QKV projection GEMM (single-term bf16) ----------
// B = [wqT | wkvT] rows: col<1024 -> Q (rope, pre-scaled by QSCALE),
// 1024..2047 -> K (rope), else V.
__global__ void __launch_bounds__(256, 3)
gemmQKV(const u16* __restrict__ Ah, const u16* __restrict__ Bt,
        u16* __restrict__ Qb, u16* __restrict__ Kb, u16* __restrict__ Vb,
        int M, int N, int K) {
  __shared__ u16 AsH[128][64];
  __shared__ u16 BsH[128][64];
  const int tid = threadIdx.x;
  const int lane = tid & 63, wave = tid >> 6;
  const int wr = wave >> 1, wc = wave & 1;
  const int lr = lane & 15, lg = lane >> 4;
  const int bm = blockIdx.y * 128, bn = blockIdx.x * 128;
  const int lrow = lane >> 3;
  const int lcol8 = (lane & 7) * 8;

  f32x4 acc[4][4];
#pragma unroll
  for (int m = 0; m < 4; ++m)
#pragma unroll
    for (int n = 0; n < 4; ++n) acc[m][n] = (f32x4){0.f, 0.f, 0.f, 0.f};

  for (int k0 = 0; k0 < K; k0 += 64) {
    __syncthreads();
#pragma unroll
    for (int c = 0; c < 4; ++c) {
      int r0 = wave * 32 + c * 8;
      size_t arow = (size_t)(bm + r0 + lrow) * K + k0 + lcol8;
      size_t brow = (size_t)(bn + r0 + lrow) * K + k0 + lcol8;
      gload16(Ah + arow, &AsH[r0][0]);
      gload16(Bt + brow, &BsH[r0][0]);
    }
    __syncthreads();
#pragma unroll
    for (int kk = 0; kk < 2; ++kk) {
      bf16x8 afh[4], bfh[4];
#pragma unroll
      for (int m = 0; m < 4; ++m)
        afh[m] = *(const bf16x8*)&AsH[wr * 64 + m * 16 + lr][kk * 32 + lg * 8];
#pragma unroll
      for (int n = 0; n < 4; ++n)
        bfh[n] = *(const bf16x8*)&BsH[wc * 64 + n * 16 + lr][kk * 32 + lg * 8];
#pragma unroll
      for (int m = 0; m < 4; ++m)
#pragma unroll
        for (int n = 0; n < 4; ++n)
          acc[m][n] = __builtin_amdgcn_mfma_f32_16x16x32_bf16(afh[m], bfh[n],
                                                              acc[m][n], 0, 0, 0);
    }
  }

  const int sel = bn >> 10;  // 0=Q, 1=K, 2=V
  u16* __restrict__ dst = sel == 0 ? Qb : (sel == 1 ? Kb : Vb);
  if (sel < 2) {  // fp32 RoPE on rotary dims
    float inv = __expf(-(float)lr * 0.5756462732485115f);
#pragma unroll
    for (int m = 0; m < 4; ++m) {
#pragma unroll
      for (int r = 0; r < 4; ++r) {
        int row = bm + wr * 64 + m * 16 + 4 * lg + r;
        int s = row & (SEQ - 1);
        float ang = (float)s * inv;
        float sn, cs;
        __sincosf(ang, &sn, &cs);
        float x1 = acc[m][0][r], x2 = acc[m][1][r];
        acc[m][0][r] = x1 * cs - x2 * sn;
        acc[m][1][r] = x2 * cs + x1 * sn;
      }
    }
  }
  const float oscale = sel == 0 ? QSCALE : 1.0f;

#pragma unroll
  for (int m = 0; m < 4; ++m) {
#pragma unroll
    for (int n = 0; n < 4; ++n) {
#pragma unroll
      for (int r = 0; r < 4; ++r) {
        int row = bm + wr * 64 + m * 16 + 4 * lg + r;
        int col = bn + wc * 64 + n * 16 + lr;
        int b = row >> 11, s = row & 2047;
        int h = (col >> 6) & 15, d = col & 63;
        dst[(((size_t)(b * NH + h)) * SEQ + s) * HD + d] =
            f2bf(acc[m][n][r] * oscale);
      }
    }
  }
}

// ---------- output projection GEMM, 128x64 tiles ----------
__global__ void __launch_bounds__(256, 2)
gemm1(const u16* __restrict__ A, const u16* __restrict__ Bt,
      float* __restrict__ CF, int M, int N, int K) {
  __shared__ u16 As[128][64];
  __shared__ u16 Bs[64][64];
  const int tid = threadIdx.x;
  const int lane = tid & 63, wave = tid >> 6;
  const int wr = wave >> 1, wc = wave & 1;
  const int lr = lane & 15, lg = lane >> 4;
  const int bm = blockIdx.y * 128, bn = blockIdx.x * 64;
  const int lrow = lane >> 3;
  const int lcol8 = (lane & 7) * 8;

  f32x4 acc[4][2];
#pragma unroll
  for (int m = 0; m < 4; ++m)
#pragma unroll
    for (int n = 0; n < 2; ++n) acc[m][n] = (f32x4){0.f, 0.f, 0.f, 0.f};

  for (int k0 = 0; k0 < K; k0 += 64) {
    __syncthreads();
#pragma unroll
    for (int c = 0; c < 4; ++c) {
      int r0 = wave * 32 + c * 8;
      gload16(A + (size_t)(bm + r0 + lrow) * K + k0 + lcol8, &As[r0][0]);
    }
#pragma unroll
    for (int c = 0; c < 2; ++c) {
      int r0 = wave * 16 + c * 8;
      gload16(Bt + (size_t)(bn + r0 + lrow) * K + k0 + lcol8, &Bs[r0][0]);
    }
    __syncthreads();
#pragma unroll
    for (int kk = 0; kk < 2; ++kk) {
      bf16x8 af[4], bfr[2];
#pragma unroll
      for (int m = 0; m < 4; ++m)
        af[m] = *(const bf16x8*)&As[wr * 64 + m * 16 + lr][kk * 32 + lg * 8];
#pragma unroll
      for (int n = 0; n < 2; ++n)
        bfr[n] = *(const bf16x8*)&Bs[wc * 32 + n * 16 + lr][kk * 32 + lg * 8];
#pragma unroll
      for (int m = 0; m < 4; ++m)
#pragma unroll
        for (int n = 0; n < 2; ++n)
          acc[m][n] = __builtin_amdgcn_mfma_f32_16x16x32_bf16(af[m], bfr[n],
                                                              acc[m][n], 0, 0, 0);
    }
  }

#pragma unroll
  for (int m = 0; m < 4; ++m)
#pragma unroll
    for (int n = 0; n < 2; ++n)
#pragma unroll
      for (int r = 0; r < 4; ++r) {
        int row = bm + wr * 64 + m * 16 + 4 * lg + r;
        int col = bn + wc * 32 + n * 16 + lr;
        CF[(size_t)row * N + col] = acc[m][n][r];
      }
}

// ---------- flash attention: 32x32 swapped-QK^T, base-2 softmax -------------
// R24 structure; partials stored as bf16 (R20-verified precision-safe).
__global__ void __launch_bounds__(256, 2)
attn_kernel(const u16* __restrict__ Q, const u16* __restrict__ K,
            const u16* __restrict__ V, u16* __restrict__ Op0,
            u16* __restrict__ Op1, float* __restrict__ ml) {
  __shared__ u16 Ks[64][72];
  __shared__ u16 Vt[64][72];  // Vt[d][kv]
  const int tid = threadIdx.x, lane = tid & 63, wave = tid >> 6;
  const int hi = lane >> 5, l31 = lane & 31;
  const int bx = blockIdx.x, bh = blockIdx.y;
  const size_t kvbase = (size_t)bh * SEQ * HD;
  const int HS = 32 * SEQ;
  const int kr0 = tid >> 3, kc0 = (tid & 7) * 8;
  const int vr = tid & 63;
  const int vc0A = (tid >> 6) * 8, vc0B = vc0A + 32;

  u16x8v kreg0, kreg1, vreg0, vreg1;

#pragma unroll 1
  for (int phase = 0; phase < 2; ++phase) {
    const int qt = phase ? 15 - bx : bx;
    const int g = phase;              // kv-half handled this phase
    const int nper = qt + 1;          // tiles in this half
    const int ktbegin = g * nper;
    const int qrow = qt * 128 + wave * 32 + l31;
    u16* __restrict__ Opart = g ? Op1 : Op0;

    const u16* qp = Q + kvbase + (size_t)qrow * HD + 8 * hi;
    bf16x8 qf0 = *(const bf16x8*)(qp);
    bf16x8 qf1 = *(const bf16x8*)(qp + 16);
    bf16x8 qf2 = *(const bf16x8*)(qp + 32);
    bf16x8 qf3 = *(const bf16x8*)(qp + 48);

    f32x16 o0 = {0.f}, o1 = {0.f};
    float m = -1e30f, l = 0.f;

    {
      const u16* kp = K + kvbase + (size_t)(ktbegin * 64) * HD;
      const u16* vp = V + kvbase + (size_t)(ktbegin * 64) * HD;
      kreg0 = *(const u16x8v*)(kp + (size_t)kr0 * HD + kc0);
      kreg1 = *(const u16x8v*)(kp + (size_t)(kr0 + 32) * HD + kc0);
      vreg0 = *(const u16x8v*)(vp + (size_t)vr * HD + vc0A);
      vreg1 = *(const u16x8v*)(vp + (size_t)vr * HD + vc0B);
    }

#pragma unroll 1
    for (int i = 0; i < nper; ++i) {
      const int kt = ktbegin + i;
      __syncthreads();
      *(u16x8v*)&Ks[kr0][kc0] = kreg0;
      *(u16x8v*)&Ks[kr0 + 32][kc0] = kreg1;
#pragma unroll
      for (int j = 0; j < 8; ++j) Vt[vc0A + j][vr] = vreg0[j];
#pragma unroll
      for (int j = 0; j < 8; ++j) Vt[vc0B + j][vr] = vreg1[j];
      __syncthreads();
      if (i + 1 < nper) {
        const u16* kp = K + kvbase + (size_t)((kt + 1) * 64) * HD;
        const u16* vp = V + kvbase + (size_t)((kt + 1) * 64) * HD;
        kreg0 = *(const u16x8v*)(kp + (size_t)kr0 * HD + kc0);
        kreg1 = *(const u16x8v*)(kp + (size_t)(kr0 + 32) * HD + kc0);
        vreg0 = *(const u16x8v*)(vp + (size_t)vr * HD + vc0A);
        vreg1 = *(const u16x8v*)(vp + (size_t)vr * HD + vc0B);
      }

      f32x16 s0 = {0.f}, s1 = {0.f};
      __builtin_amdgcn_s_setprio(1);
#pragma unroll
      for (int kk = 0; kk < 4; ++kk) {
        bf16x8 qk = kk == 0 ? qf0 : (kk == 1 ? qf1 : (kk == 2 ? qf2 : qf3));
        bf16x8 af0 = *(const bf16x8*)&Ks[l31][16 * kk + 8 * hi];
        bf16x8 af1 = *(const bf16x8*)&Ks[32 + l31][16 * kk + 8 * hi];
        s0 = __builtin_amdgcn_mfma_f32_32x32x16_bf16(af0, qk, s0, 0, 0, 0);
        s1 = __builtin_amdgcn_mfma_f32_32x32x16_bf16(af1, qk, s1, 0, 0, 0);
      }
      __builtin_amdgcn_s_setprio(0);
      // no scaling: Q was pre-scaled; S already in log2 domain

      if (kt >= 2 * qt) {  // diagonal tiles: mask kv > q
#pragma unroll
        for (int r = 0; r < 16; ++r) {
          int rowi = (r & 3) + 8 * (r >> 2) + 4 * hi;
          if (kt * 64 + rowi > qrow) s0[r] = -1e30f;
          if (kt * 64 + 32 + rowi > qrow) s1[r] = -1e30f;
        }
      }

      float mx = s0[0];
#pragma unroll
      for (int r = 1; r < 16; ++r) mx = fmaxf(mx, s0[r]);
#pragma unroll
      for (int r = 0; r < 16; ++r) mx = fmaxf(mx, s1[r]);
      mx = fmaxf(mx, __shfl_xor(mx, 32));

      bool defer = __all(mx - m <= DEFER_THR);
      if (!defer) {
        float mn = fmaxf(m, mx);
        float fac = exp2f(m - mn);
        m = mn;
        l *= fac;
        o0 *= fac;
        o1 *= fac;
      }
      float rsum = 0.f;
#pragma unroll
      for (int r = 0; r < 16; ++r) {
        s0[r] = exp2f(s0[r] - m);
        rsum += s0[r];
      }
#pragma unroll
      for (int r = 0; r < 16; ++r) {
        s1[r] = exp2f(s1[r] - m);
        rsum += s1[r];
      }
      rsum += __shfl_xor(rsum, 32);
      l += rsum;

      u32 P0a[4], P1a[4], P0b[4], P1b[4];
#pragma unroll
      for (int gg = 0; gg < 4; ++gg) {
        P0a[gg] = cvtpk(s0[4 * gg], s0[4 * gg + 1]);
        P1a[gg] = cvtpk(s0[4 * gg + 2], s0[4 * gg + 3]);
        P0b[gg] = cvtpk(s1[4 * gg], s1[4 * gg + 1]);
        P1b[gg] = cvtpk(s1[4 * gg + 2], s1[4 * gg + 3]);
      }

      __builtin_amdgcn_s_setprio(1);
#pragma unroll
      for (int c = 0; c < 4; ++c) {
        const int gA = 2 * (c & 1);
        u32 p0lo, p0hi, p1lo, p1hi;
        if (c < 2) {
          p0lo = P0a[gA];
          p0hi = P0a[gA + 1];
          p1lo = P1a[gA];
          p1hi = P1a[gA + 1];
        } else {
          p0lo = P0b[gA];
          p0hi = P0b[gA + 1];
          p1lo = P1b[gA];
          p1hi = P1b[gA + 1];
        }
        u32 send0 = hi ? p0lo : p0hi;
        u32 send1 = hi ? p1lo : p1hi;
        u32 recv0 = (u32)__shfl_xor((int)send0, 32);
        u32 recv1 = (u32)__shfl_xor((int)send1, 32);
        u32 own0 = hi ? p0hi : p0lo;
        u32 own1 = hi ? p1hi : p1lo;
        u32x4 bw;
        bw[0] = hi ? recv0 : own0;
        bw[1] = hi ? recv1 : own1;
        bw[2] = hi ? own0 : recv0;
        bw[3] = hi ? own1 : recv1;
        bf16x8 bfrag = __builtin_bit_cast(bf16x8, bw);
        bf16x8 av0 = *(const bf16x8*)&Vt[l31][16 * c + 8 * hi];
        bf16x8 av1 = *(const bf16x8*)&Vt[32 + l31][16 * c + 8 * hi];
        o0 = __builtin_amdgcn_mfma_f32_32x32x16_bf16(av0, bfrag, o0, 0, 0, 0);
        o1 = __builtin_amdgcn_mfma_f32_32x32x16_bf16(av1, bfrag, o1, 0, 0, 0);
      }
      __builtin_amdgcn_s_setprio(0);
    }

    // epilogue: premultiplied O^T partial -> Opart[bh][s][d] (bf16), m/l (f32)
    {
      size_t base = ((size_t)bh * SEQ + qrow) * HD;
#pragma unroll
      for (int gg = 0; gg < 4; ++gg) {
        u32x2 w0, w1;
        w0[0] = cvtpk(o0[4 * gg], o0[4 * gg + 1]);
        w0[1] = cvtpk(o0[4 * gg + 2], o0[4 * gg + 3]);
        w1[0] = cvtpk(o1[4 * gg], o1[4 * gg + 1]);
        w1[1] = cvtpk(o1[4 * gg + 2], o1[4 * gg + 3]);
        *(u32x2*)(Opart + base + 8 * gg + 4 * hi) = w0;
        *(u32x2*)(Opart + base + 32 + 8 * gg + 4 * hi) = w1;
      }
      if (hi == 0) {
        ml[g * HS + bh * SEQ + qrow] = m;
        ml[2 * HS + g * HS + bh * SEQ + qrow] = l;
      }
    }
    __syncthreads();  // protect LDS before next phase's staging
  }
}

// ---------- merge the two KV-half partials (bf16), write bf16 O -------------
// m values are in log2 domain -> exp2f weights.
__global__ void merge_kernel(const u16* __restrict__ P0,
                             const u16* __restrict__ P1,
                             const float* __restrict__ ml,
                             u16* __restrict__ O) {
  int i = blockIdx.x * 256 + threadIdx.x;
  int row = i >> 4;  // bh*SEQ + s
  int d0 = (i & 15) * 4;
  size_t base = (size_t)row * 64 + d0;
  u16x4v p0 = *(const u16x4v*)(P0 + base);
  u16x4v p1 = *(const u16x4v*)(P1 + base);
  const int HS = 32 * SEQ;
  float m1 = ml[row], m2 = ml[HS + row];
  float l1 = ml[2 * HS + row], l2 = ml[3 * HS + row];
  float M = fmaxf(m1, m2);
  float w1 = exp2f(m1 - M), w2 = exp2f(m2 - M);
  float inv = 1.0f / (l1 * w1 + l2 * w2);
  int bh = row >> 11, s = row & 2047;
  int b = bh >> 4, h = bh & 15;
  u16x4v rr;
#pragma unroll
  for (int j = 0; j < 4; ++j)
    rr[j] = f2bf((bf2f(p0[j]) * w1 + bf2f(p1[j]) * w2) * inv);
  *(u16x4v*)(O + ((size_t)(b * SEQ + s)) * DIMM + h * HD + d0) = rr;
}

extern "C" void kernel_launch(void* const* d_in, const int* in_sizes, int n_in,
                              void* d_out, int out_size, void* d_ws, size_t ws_size,
                              hipStream_t stream) {
  const float* x = (const float*)d_in[0];
  const float* wq = (const float*)d_in[1];
  const float* wkv = (const float*)d_in[2];
  const float* wout = (const float*)d_in[3];
  float* out = (float*)d_out;

  u16* ws = (u16*)d_ws;
  const size_t M1 = (size_t)1024 * 1024;
  u16* xh = ws;                    // 4M u16 (dead after gemmQKV -> Op1 overlay)
  u16* xl = xh + 4 * M1;           // 4M (unused slab)
  u16* wqTh = xl + 4 * M1;         // 1M  (wkvTh contiguous -> B[3072][1024])
  u16* wkvTh = wqTh + M1;          // 2M
  u16* Qb = wkvTh + 2 * M1;        // 4M
  u16* Kb = Qb + 4 * M1;           // 4M
  u16* Vb = Kb + 4 * M1;           // 4M
  // overlays:
  u16* Op0 = (u16*)out;            // bf16 partial, 8MB of out's 16MB
  u16* Op1 = xh;                   // bf16 partial, 8MB (x dead after gemmQKV)
  float* mlbuf = (float*)wqTh;     // 1MB need; 2MB slab
  u16* Ob = Qb;                    // 8MB need; Qb dead after attn
  u16* woutT = Kb;                 // 2MB need; Kb dead after attn

  conv_x<<<4096, 256, 0, stream>>>(x, xh);
  conv_wT<<<dim3(32, 32), 256, 0, stream>>>(wq, wqTh, 1024, 1024);
  conv_wT<<<dim3(64, 32), 256, 0, stream>>>(wkv, wkvTh, 1024, 2048);

  gemmQKV<<<dim3(24, 32), 256, 0, stream>>>(xh, wqTh, Qb, Kb, Vb,
                                            4096, 3072, 1024);

  attn_kernel<<<dim3(16, 32), 256, 0, stream>>>(Qb, Kb, Vb, Op0, Op1, mlbuf);
  merge_kernel<<<4096, 256, 0, stream>>>(Op0, Op1, mlbuf, Ob);

  conv_wT<<<dim3(32, 32), 256, 0, stream>>>(wout, woutT, 1024, 1024);
  gemm1<<<dim3(16, 32), 256, 0, stream>>>(Ob, woutT, out, 4096, 1024, 1024);
}

// Round 28
// 120.972 us; speedup vs baseline: 1.0409x; 1.0040x over previous
//
#include <hip/hip_runtime.h>

typedef unsigned short u16;
typedef unsigned int u32;
typedef __bf16 bf16x8 __attribute__((ext_vector_type(8)));
typedef unsigned short u16x8v __attribute__((ext_vector_type(8)));
typedef unsigned short u16x4v __attribute__((ext_vector_type(4)));
typedef unsigned int u32x2 __attribute__((ext_vector_type(2)));
typedef unsigned int u32x4 __attribute__((ext_vector_type(4)));
typedef float f32x4 __attribute__((ext_vector_type(4)));
typedef float f32x16 __attribute__((ext_vector_type(16)));

#define SEQ 2048
#define NH 16
#define HD 64
#define DIMM 1024
// softmax scale folded into Q: 1/sqrt(64) * log2(e)
#define QSCALE 0.18033688f
// defer-max threshold in log2 units (= 8 nats)
#define DEFER_THR 11.5417f

__device__ __forceinline__ u16 f2bf(float f) {
  unsigned u = __builtin_bit_cast(unsigned, f);
  u += 0x7fffu + ((u >> 16) & 1u);
  return (u16)(u >> 16);
}
__device__ __forceinline__ float bf2f(u16 b) {
  return __builtin_bit_cast(float, ((unsigned)b) << 16);
}
// RTNE pack of two f32 -> packed bf16 pair, single HW instruction
__device__ __forceinline__ u32 cvtpk(float a, float b) {
  u32 r;
  asm("v_cvt_pk_bf16_f32 %0, %1, %2" : "=v"(r) : "v"(a), "v"(b));
  return r;
}

// async global->LDS, 16B per lane; LDS dest = wave-uniform base + lane*16
__device__ __forceinline__ void gload16(const u16* g, u16* l) {
  __builtin_amdgcn_global_load_lds(
      (const __attribute__((address_space(1))) unsigned int*)g,
      (__attribute__((address_space(3))) unsigned int*)l, 16, 0, 0);
}

// ---------- convert x (f32 -> bf16) ----------
__global__ void conv_x(const float* __restrict__ x, u16* __restrict__ oh) {
  size_t i = (size_t)blockIdx.x * 256 + threadIdx.x;
  f32x4 v = *(const f32x4*)(x + i * 4);
  u16x4v h;
#pragma unroll
  for (int j = 0; j < 4; ++j) h[j] = f2bf(v[j]);
  *(u16x4v*)(oh + i * 4) = h;
}

// ---------- transpose: W[K][N] f32 -> Wt[N][K] bf16 ----------
__global__ void conv_wT(const float* __restrict__ W, u16* __restrict__ Wt,
                        int Kd, int Nd) {
  __shared__ float t[32][33];
  int n0 = blockIdx.x * 32, k0 = blockIdx.y * 32;
  int c = threadIdx.x & 31, r8 = threadIdx.x >> 5;
#pragma unroll
  for (int rr = 0; rr < 32; rr += 8)
    t[r8 + rr][c] = W[(size_t)(k0 + r8 + rr) * Nd + n0 + c];
  __syncthreads();
#pragma unroll
  for (int rr = 0; rr < 32; rr += 8)
    Wt[(size_t)(n0 + r8 + rr) * Kd + k0 + c] = f2bf(t[c][r8 + rr]);
}

// ---------- combined QKV projection GEMM (single-term bf16) ----------
// B = [wqT | wkvT] rows: col<1024 -> Q (rope, pre-scaled by QSCALE),
// 1024..2047 -> K (rope), else V.
__global__ void __launch_bounds__(256, 3)
gemmQKV(const u16* __restrict__ Ah, const u16* __restrict__ Bt,
        u16* __restrict__ Qb, u16* __restrict__ Kb, u16* __restrict__ Vb,
        int M, int N, int K) {
  __shared__ u16 AsH[128][64];
  __shared__ u16 BsH[128][64];
  const int tid = threadIdx.x;
  const int lane = tid & 63, wave = tid >> 6;
  const int wr = wave >> 1, wc = wave & 1;
  const int lr = lane & 15, lg = lane >> 4;
  const int bm = blockIdx.y * 128, bn = blockIdx.x * 128;
  const int lrow = lane >> 3;
  const int lcol8 = (lane & 7) * 8;

  f32x4 acc[4][4];
#pragma unroll
  for (int m = 0; m < 4; ++m)
#pragma unroll
    for (int n = 0; n < 4; ++n) acc[m][n] = (f32x4){0.f, 0.f, 0.f, 0.f};

  for (int k0 = 0; k0 < K; k0 += 64) {
    __syncthreads();
#pragma unroll
    for (int c = 0; c < 4; ++c) {
      int r0 = wave * 32 + c * 8;
      size_t arow = (size_t)(bm + r0 + lrow) * K + k0 + lcol8;
      size_t brow = (size_t)(bn + r0 + lrow) * K + k0 + lcol8;
      gload16(Ah + arow, &AsH[r0][0]);
      gload16(Bt + brow, &BsH[r0][0]);
    }
    __syncthreads();
#pragma unroll
    for (int kk = 0; kk < 2; ++kk) {
      bf16x8 afh[4], bfh[4];
#pragma unroll
      for (int m = 0; m < 4; ++m)
        afh[m] = *(const bf16x8*)&AsH[wr * 64 + m * 16 + lr][kk * 32 + lg * 8];
#pragma unroll
      for (int n = 0; n < 4; ++n)
        bfh[n] = *(const bf16x8*)&BsH[wc * 64 + n * 16 + lr][kk * 32 + lg * 8];
#pragma unroll
      for (int m = 0; m < 4; ++m)
#pragma unroll
        for (int n = 0; n < 4; ++n)
          acc[m][n] = __builtin_amdgcn_mfma_f32_16x16x32_bf16(afh[m], bfh[n],
                                                              acc[m][n], 0, 0, 0);
    }
  }

  const int sel = bn >> 10;  // 0=Q, 1=K, 2=V
  u16* __restrict__ dst = sel == 0 ? Qb : (sel == 1 ? Kb : Vb);
  if (sel < 2) {  // fp32 RoPE on rotary dims
    float inv = __expf(-(float)lr * 0.5756462732485115f);
#pragma unroll
    for (int m = 0; m < 4; ++m) {
#pragma unroll
      for (int r = 0; r < 4; ++r) {
        int row = bm + wr * 64 + m * 16 + 4 * lg + r;
        int s = row & (SEQ - 1);
        float ang = (float)s * inv;
        float sn, cs;
        __sincosf(ang, &sn, &cs);
        float x1 = acc[m][0][r], x2 = acc[m][1][r];
        acc[m][0][r] = x1 * cs - x2 * sn;
        acc[m][1][r] = x2 * cs + x1 * sn;
      }
    }
  }
  const float oscale = sel == 0 ? QSCALE : 1.0f;

#pragma unroll
  for (int m = 0; m < 4; ++m) {
#pragma unroll
    for (int n = 0; n < 4; ++n) {
#pragma unroll
      for (int r = 0; r < 4; ++r) {
        int row = bm + wr * 64 + m * 16 + 4 * lg + r;
        int col = bn + wc * 64 + n * 16 + lr;
        int b = row >> 11, s = row & 2047;
        int h = (col >> 6) & 15, d = col & 63;
        dst[(((size_t)(b * NH + h)) * SEQ + s) * HD + d] =
            f2bf(acc[m][n][r] * oscale);
      }
    }
  }
}

// ---------- output projection GEMM, 128x64 tiles ----------
__global__ void __launch_bounds__(256, 2)
gemm1(const u16* __restrict__ A, const u16* __restrict__ Bt,
      float* __restrict__ CF, int M, int N, int K) {
  __shared__ u16 As[128][64];
  __shared__ u16 Bs[64][64];
  const int tid = threadIdx.x;
  const int lane = tid & 63, wave = tid >> 6;
  const int wr = wave >> 1, wc = wave & 1;
  const int lr = lane & 15, lg = lane >> 4;
  const int bm = blockIdx.y * 128, bn = blockIdx.x * 64;
  const int lrow = lane >> 3;
  const int lcol8 = (lane & 7) * 8;

  f32x4 acc[4][2];
#pragma unroll
  for (int m = 0; m < 4; ++m)
#pragma unroll
    for (int n = 0; n < 2; ++n) acc[m][n] = (f32x4){0.f, 0.f, 0.f, 0.f};

  for (int k0 = 0; k0 < K; k0 += 64) {
    __syncthreads();
#pragma unroll
    for (int c = 0; c < 4; ++c) {
      int r0 = wave * 32 + c * 8;
      gload16(A + (size_t)(bm + r0 + lrow) * K + k0 + lcol8, &As[r0][0]);
    }
#pragma unroll
    for (int c = 0; c < 2; ++c) {
      int r0 = wave * 16 + c * 8;
      gload16(Bt + (size_t)(bn + r0 + lrow) * K + k0 + lcol8, &Bs[r0][0]);
    }
    __syncthreads();
#pragma unroll
    for (int kk = 0; kk < 2; ++kk) {
      bf16x8 af[4], bfr[2];
#pragma unroll
      for (int m = 0; m < 4; ++m)
        af[m] = *(const bf16x8*)&As[wr * 64 + m * 16 + lr][kk * 32 + lg * 8];
#pragma unroll
      for (int n = 0; n < 2; ++n)
        bfr[n] = *(const bf16x8*)&Bs[wc * 32 + n * 16 + lr][kk * 32 + lg * 8];
#pragma unroll
      for (int m = 0; m < 4; ++m)
#pragma unroll
        for (int n = 0; n < 2; ++n)
          acc[m][n] = __builtin_amdgcn_mfma_f32_16x16x32_bf16(af[m], bfr[n],
                                                              acc[m][n], 0, 0, 0);
    }
  }

#pragma unroll
  for (int m = 0; m < 4; ++m)
#pragma unroll
    for (int n = 0; n < 2; ++n)
#pragma unroll
      for (int r = 0; r < 4; ++r) {
        int row = bm + wr * 64 + m * 16 + 4 * lg + r;
        int col = bn + wc * 32 + n * 16 + lr;
        CF[(size_t)row * N + col] = acc[m][n][r];
      }
}

// ---------- flash attention: 32x32 swapped-QK^T, base-2 softmax -------------
// R24 structure; partials stored as bf16 (R20-verified precision-safe).
__global__ void __launch_bounds__(256, 2)
attn_kernel(const u16* __restrict__ Q, const u16* __restrict__ K,
            const u16* __restrict__ V, u16* __restrict__ Op0,
            u16* __restrict__ Op1, float* __restrict__ ml) {
  __shared__ u16 Ks[64][72];
  __shared__ u16 Vt[64][72];  // Vt[d][kv]
  const int tid = threadIdx.x, lane = tid & 63, wave = tid >> 6;
  const int hi = lane >> 5, l31 = lane & 31;
  const int bx = blockIdx.x, bh = blockIdx.y;
  const size_t kvbase = (size_t)bh * SEQ * HD;
  const int HS = 32 * SEQ;
  const int kr0 = tid >> 3, kc0 = (tid & 7) * 8;
  const int vr = tid & 63;
  const int vc0A = (tid >> 6) * 8, vc0B = vc0A + 32;

  u16x8v kreg0, kreg1, vreg0, vreg1;

#pragma unroll 1
  for (int phase = 0; phase < 2; ++phase) {
    const int qt = phase ? 15 - bx : bx;
    const int g = phase;              // kv-half handled this phase
    const int nper = qt + 1;          // tiles in this half
    const int ktbegin = g * nper;
    const int qrow = qt * 128 + wave * 32 + l31;
    u16* __restrict__ Opart = g ? Op1 : Op0;

    const u16* qp = Q + kvbase + (size_t)qrow * HD + 8 * hi;
    bf16x8 qf0 = *(const bf16x8*)(qp);
    bf16x8 qf1 = *(const bf16x8*)(qp + 16);
    bf16x8 qf2 = *(const bf16x8*)(qp + 32);
    bf16x8 qf3 = *(const bf16x8*)(qp + 48);

    f32x16 o0 = {0.f}, o1 = {0.f};
    float m = -1e30f, l = 0.f;

    {
      const u16* kp = K + kvbase + (size_t)(ktbegin * 64) * HD;
      const u16* vp = V + kvbase + (size_t)(ktbegin * 64) * HD;
      kreg0 = *(const u16x8v*)(kp + (size_t)kr0 * HD + kc0);
      kreg1 = *(const u16x8v*)(kp + (size_t)(kr0 + 32) * HD + kc0);
      vreg0 = *(const u16x8v*)(vp + (size_t)vr * HD + vc0A);
      vreg1 = *(const u16x8v*)(vp + (size_t)vr * HD + vc0B);
    }

#pragma unroll 1
    for (int i = 0; i < nper; ++i) {
      const int kt = ktbegin + i;
      __syncthreads();
      *(u16x8v*)&Ks[kr0][kc0] = kreg0;
      *(u16x8v*)&Ks[kr0 + 32][kc0] = kreg1;
#pragma unroll
      for (int j = 0; j < 8; ++j) Vt[vc0A + j][vr] = vreg0[j];
#pragma unroll
      for (int j = 0; j < 8; ++j) Vt[vc0B + j][vr] = vreg1[j];
      __syncthreads();
      if (i + 1 < nper) {
        const u16* kp = K + kvbase + (size_t)((kt + 1) * 64) * HD;
        const u16* vp = V + kvbase + (size_t)((kt + 1) * 64) * HD;
        kreg0 = *(const u16x8v*)(kp + (size_t)kr0 * HD + kc0);
        kreg1 = *(const u16x8v*)(kp + (size_t)(kr0 + 32) * HD + kc0);
        vreg0 = *(const u16x8v*)(vp + (size_t)vr * HD + vc0A);
        vreg1 = *(const u16x8v*)(vp + (size_t)vr * HD + vc0B);
      }

      f32x16 s0 = {0.f}, s1 = {0.f};
      __builtin_amdgcn_s_setprio(1);
#pragma unroll
      for (int kk = 0; kk < 4; ++kk) {
        bf16x8 qk = kk == 0 ? qf0 : (kk == 1 ? qf1 : (kk == 2 ? qf2 : qf3));
        bf16x8 af0 = *(const bf16x8*)&Ks[l31][16 * kk + 8 * hi];
        bf16x8 af1 = *(const bf16x8*)&Ks[32 + l31][16 * kk + 8 * hi];
        s0 = __builtin_amdgcn_mfma_f32_32x32x16_bf16(af0, qk, s0, 0, 0, 0);
        s1 = __builtin_amdgcn_mfma_f32_32x32x16_bf16(af1, qk, s1, 0, 0, 0);
      }
      __builtin_amdgcn_s_setprio(0);
      // no scaling: Q was pre-scaled; S already in log2 domain

      if (kt >= 2 * qt) {  // diagonal tiles: mask kv > q
#pragma unroll
        for (int r = 0; r < 16; ++r) {
          int rowi = (r & 3) + 8 * (r >> 2) + 4 * hi;
          if (kt * 64 + rowi > qrow) s0[r] = -1e30f;
          if (kt * 64 + 32 + rowi > qrow) s1[r] = -1e30f;
        }
      }

      float mx = s0[0];
#pragma unroll
      for (int r = 1; r < 16; ++r) mx = fmaxf(mx, s0[r]);
#pragma unroll
      for (int r = 0; r < 16; ++r) mx = fmaxf(mx, s1[r]);
      mx = fmaxf(mx, __shfl_xor(mx, 32));

      bool defer = __all(mx - m <= DEFER_THR);
      if (!defer) {
        float mn = fmaxf(m, mx);
        float fac = exp2f(m - mn);
        m = mn;
        l *= fac;
        o0 *= fac;
        o1 *= fac;
      }
      float rsum = 0.f;
#pragma unroll
      for (int r = 0; r < 16; ++r) {
        s0[r] = exp2f(s0[r] - m);
        rsum += s0[r];
      }
#pragma unroll
      for (int r = 0; r < 16; ++r) {
        s1[r] = exp2f(s1[r] - m);
        rsum += s1[r];
      }
      rsum += __shfl_xor(rsum, 32);
      l += rsum;

      u32 P0a[4], P1a[4], P0b[4], P1b[4];
#pragma unroll
      for (int gg = 0; gg < 4; ++gg) {
        P0a[gg] = cvtpk(s0[4 * gg], s0[4 * gg + 1]);
        P1a[gg] = cvtpk(s0[4 * gg + 2], s0[4 * gg + 3]);
        P0b[gg] = cvtpk(s1[4 * gg], s1[4 * gg + 1]);
        P1b[gg] = cvtpk(s1[4 * gg + 2], s1[4 * gg + 3]);
      }

      __builtin_amdgcn_s_setprio(1);
#pragma unroll
      for (int c = 0; c < 4; ++c) {
        const int gA = 2 * (c & 1);
        u32 p0lo, p0hi, p1lo, p1hi;
        if (c < 2) {
          p0lo = P0a[gA];
          p0hi = P0a[gA + 1];
          p1lo = P1a[gA];
          p1hi = P1a[gA + 1];
        } else {
          p0lo = P0b[gA];
          p0hi = P0b[gA + 1];
          p1lo = P1b[gA];
          p1hi = P1b[gA + 1];
        }
        u32 send0 = hi ? p0lo : p0hi;
        u32 send1 = hi ? p1lo : p1hi;
        u32 recv0 = (u32)__shfl_xor((int)send0, 32);
        u32 recv1 = (u32)__shfl_xor((int)send1, 32);
        u32 own0 = hi ? p0hi : p0lo;
        u32 own1 = hi ? p1hi : p1lo;
        u32x4 bw;
        bw[0] = hi ? recv0 : own0;
        bw[1] = hi ? recv1 : own1;
        bw[2] = hi ? own0 : recv0;
        bw[3] = hi ? own1 : recv1;
        bf16x8 bfrag = __builtin_bit_cast(bf16x8, bw);
        bf16x8 av0 = *(const bf16x8*)&Vt[l31][16 * c + 8 * hi];
        bf16x8 av1 = *(const bf16x8*)&Vt[32 + l31][16 * c + 8 * hi];
        o0 = __builtin_amdgcn_mfma_f32_32x32x16_bf16(av0, bfrag, o0, 0, 0, 0);
        o1 = __builtin_amdgcn_mfma_f32_32x32x16_bf16(av1, bfrag, o1, 0, 0, 0);
      }
      __builtin_amdgcn_s_setprio(0);
    }

    // epilogue: premultiplied O^T partial -> Opart[bh][s][d] (bf16), m/l (f32)
    {
      size_t base = ((size_t)bh * SEQ + qrow) * HD;
#pragma unroll
      for (int gg = 0; gg < 4; ++gg) {
        u32x2 w0, w1;
        w0[0] = cvtpk(o0[4 * gg], o0[4 * gg + 1]);
        w0[1] = cvtpk(o0[4 * gg + 2], o0[4 * gg + 3]);
        w1[0] = cvtpk(o1[4 * gg], o1[4 * gg + 1]);
        w1[1] = cvtpk(o1[4 * gg + 2], o1[4 * gg + 3]);
        *(u32x2*)(Opart + base + 8 * gg + 4 * hi) = w0;
        *(u32x2*)(Opart + base + 32 + 8 * gg + 4 * hi) = w1;
      }
      if (hi == 0) {
        ml[g * HS + bh * SEQ + qrow] = m;
        ml[2 * HS + g * HS + bh * SEQ + qrow] = l;
      }
    }
    __syncthreads();  // protect LDS before next phase's staging
  }
}

// ---------- merge the two KV-half partials (bf16), write bf16 O -------------
// m values are in log2 domain -> exp2f weights.
__global__ void merge_kernel(const u16* __restrict__ P0,
                             const u16* __restrict__ P1,
                             const float* __restrict__ ml,
                             u16* __restrict__ O) {
  int i = blockIdx.x * 256 + threadIdx.x;
  int row = i >> 4;  // bh*SEQ + s
  int d0 = (i & 15) * 4;
  size_t base = (size_t)row * 64 + d0;
  u16x4v p0 = *(const u16x4v*)(P0 + base);
  u16x4v p1 = *(const u16x4v*)(P1 + base);
  const int HS = 32 * SEQ;
  float m1 = ml[row], m2 = ml[HS + row];
  float l1 = ml[2 * HS + row], l2 = ml[3 * HS + row];
  float M = fmaxf(m1, m2);
  float w1 = exp2f(m1 - M), w2 = exp2f(m2 - M);
  float inv = 1.0f / (l1 * w1 + l2 * w2);
  int bh = row >> 11, s = row & 2047;
  int b = bh >> 4, h = bh & 15;
  u16x4v rr;
#pragma unroll
  for (int j = 0; j < 4; ++j)
    rr[j] = f2bf((bf2f(p0[j]) * w1 + bf2f(p1[j]) * w2) * inv);
  *(u16x4v*)(O + ((size_t)(b * SEQ + s)) * DIMM + h * HD + d0) = rr;
}

extern "C" void kernel_launch(void* const* d_in, const int* in_sizes, int n_in,
                              void* d_out, int out_size, void* d_ws, size_t ws_size,
                              hipStream_t stream) {
  const float* x = (const float*)d_in[0];
  const float* wq = (const float*)d_in[1];
  const float* wkv = (const float*)d_in[2];
  const float* wout = (const float*)d_in[3];
  float* out = (float*)d_out;

  u16* ws = (u16*)d_ws;
  const size_t M1 = (size_t)1024 * 1024;
  u16* xh = ws;                    // 4M u16 (dead after gemmQKV -> Op1 overlay)
  u16* xl = xh + 4 * M1;           // 4M (unused slab)
  u16* wqTh = xl + 4 * M1;         // 1M  (wkvTh contiguous -> B[3072][1024])
  u16* wkvTh = wqTh + M1;          // 2M
  u16* Qb = wkvTh + 2 * M1;        // 4M
  u16* Kb = Qb + 4 * M1;           // 4M
  u16* Vb = Kb + 4 * M1;           // 4M
  // overlays:
  u16* Op0 = (u16*)out;            // bf16 partial, 8MB of out's 16MB
  u16* Op1 = xh;                   // bf16 partial, 8MB (x dead after gemmQKV)
  float* mlbuf = (float*)wqTh;     // 1MB need; 2MB slab
  u16* Ob = Qb;                    // 8MB need; Qb dead after attn
  u16* woutT = Kb;                 // 2MB need; Kb dead after attn

  conv_x<<<4096, 256, 0, stream>>>(x, xh);
  conv_wT<<<dim3(32, 32), 256, 0, stream>>>(wq, wqTh, 1024, 1024);
  conv_wT<<<dim3(64, 32), 256, 0, stream>>>(wkv, wkvTh, 1024, 2048);

  gemmQKV<<<dim3(24, 32), 256, 0, stream>>>(xh, wqTh, Qb, Kb, Vb,
                                            4096, 3072, 1024);

  attn_kernel<<<dim3(16, 32), 256, 0, stream>>>(Qb, Kb, Vb, Op0, Op1, mlbuf);
  merge_kernel<<<4096, 256, 0, stream>>>(Op0, Op1, mlbuf, Ob);

  conv_wT<<<dim3(32, 32), 256, 0, stream>>>(wout, woutT, 1024, 1024);
  gemm1<<<dim3(16, 32), 256, 0, stream>>>(Ob, woutT, out, 4096, 1024, 1024);
}